// Round 1
// baseline (39.074 us; speedup 1.0000x reference)
//
#include <hip/hip_runtime.h>

// HammingLoss: loss = mean_i popcount(code[output[i]] ^ code[target[i]])
// where code[c] is the 64-bit packing of coding_table[c, :] (values 0/1).
//
// ws layout:
//   [0, 8000)   : unsigned long long codes[1000]
//   [8192]      : unsigned long long accumulator

#define N_CLASSES 1000
#define CODE_LEN  64

__global__ void pack_codes_kernel(const float* __restrict__ table,
                                  unsigned long long* __restrict__ codes,
                                  unsigned long long* __restrict__ acc) {
    // zero the accumulator (ws is poisoned 0xAA by the harness, never re-poisoned)
    if (blockIdx.x == 0 && threadIdx.x == 0) *acc = 0ULL;

    int gtid = blockIdx.x * blockDim.x + threadIdx.x;
    int wave = gtid >> 6;          // one wave (64 lanes) per class
    int lane = threadIdx.x & 63;
    if (wave < N_CLASSES) {
        float v = table[wave * CODE_LEN + lane];          // coalesced
        unsigned long long mask = __ballot(v > 0.5f);     // 64-bit ballot
        if (lane == 0) codes[wave] = mask;
    }
}

__global__ void __launch_bounds__(256)
hamming_kernel(const int* __restrict__ out_idx,
               const int* __restrict__ tgt_idx,
               const unsigned long long* __restrict__ codes,
               unsigned long long* __restrict__ acc,
               int nvec, int n) {
    __shared__ unsigned long long s_codes[N_CLASSES];
    for (int i = threadIdx.x; i < N_CLASSES; i += blockDim.x)
        s_codes[i] = codes[i];
    __syncthreads();

    const int4* o4 = (const int4*)out_idx;
    const int4* t4 = (const int4*)tgt_idx;

    int sum = 0;
    int stride = gridDim.x * blockDim.x;
    for (int i = blockIdx.x * blockDim.x + threadIdx.x; i < nvec; i += stride) {
        int4 o = o4[i];
        int4 t = t4[i];
        sum += __popcll(s_codes[o.x] ^ s_codes[t.x]);
        sum += __popcll(s_codes[o.y] ^ s_codes[t.y]);
        sum += __popcll(s_codes[o.z] ^ s_codes[t.z]);
        sum += __popcll(s_codes[o.w] ^ s_codes[t.w]);
    }
    // scalar tail (n not divisible by 4)
    for (int i = nvec * 4 + blockIdx.x * blockDim.x + threadIdx.x; i < n; i += stride) {
        sum += __popcll(s_codes[out_idx[i]] ^ s_codes[tgt_idx[i]]);
    }

    // wave (64-lane) butterfly reduce
    #pragma unroll
    for (int off = 32; off >= 1; off >>= 1)
        sum += __shfl_down(sum, off);

    __shared__ int s_part[4];      // 256 threads = 4 waves
    int wid  = threadIdx.x >> 6;
    int lane = threadIdx.x & 63;
    if (lane == 0) s_part[wid] = sum;
    __syncthreads();
    if (threadIdx.x == 0) {
        int tot = s_part[0] + s_part[1] + s_part[2] + s_part[3];
        atomicAdd(acc, (unsigned long long)tot);
    }
}

__global__ void finalize_kernel(const unsigned long long* __restrict__ acc,
                                float* __restrict__ out, int n) {
    if (threadIdx.x == 0 && blockIdx.x == 0) {
        out[0] = (float)((double)(*acc) / (double)n);
    }
}

extern "C" void kernel_launch(void* const* d_in, const int* in_sizes, int n_in,
                              void* d_out, int out_size, void* d_ws, size_t ws_size,
                              hipStream_t stream) {
    const int*   out_idx = (const int*)d_in[0];
    const int*   tgt_idx = (const int*)d_in[1];
    const float* table   = (const float*)d_in[2];
    float*       out     = (float*)d_out;

    int n = in_sizes[0];

    unsigned long long* codes = (unsigned long long*)d_ws;
    unsigned long long* acc   = (unsigned long long*)((char*)d_ws + 8192);

    // 1) pack table -> 64-bit codes, zero accumulator
    {
        int waves_needed = N_CLASSES;
        int threads = 256;                       // 4 waves/block
        int blocks = (waves_needed * 64 + threads - 1) / threads;
        pack_codes_kernel<<<blocks, threads, 0, stream>>>(table, codes, acc);
    }

    // 2) main reduce
    {
        int nvec = n / 4;
        int threads = 256;
        int blocks = (nvec + threads - 1) / threads;
        if (blocks > 2048) blocks = 2048;
        if (blocks < 1) blocks = 1;
        hamming_kernel<<<blocks, threads, 0, stream>>>(out_idx, tgt_idx, codes,
                                                       acc, nvec, n);
    }

    // 3) finalize scalar
    finalize_kernel<<<1, 64, 0, stream>>>(acc, out, n);
}

// Round 2
// 37.948 us; speedup vs baseline: 1.0297x; 1.0297x over previous
//
#include <hip/hip_runtime.h>

// HammingLoss: loss = mean_i popcount(code[output[i]] ^ code[target[i]])
// code[c] = 64-bit packing of coding_table[c, :] (values are exactly 0.0/1.0).
//
// 2 dispatches:
//   1) pack_init: table -> packed u64 codes; zero acc + counter (ws is poisoned
//      0xAA once and never re-poisoned, so every call must self-init).
//   2) hamming_finalize: LDS-staged popcount reduce + last-block-done finalize
//      (release fence -> counter; last block acquire-fences and atomically
//      re-reads acc -- correct across non-coherent per-XCD L2s).
//
// ws layout:
//   [0,    8000) : unsigned long long codes[1000]
//   [8192, 8200) : unsigned long long acc
//   [8200, 8204) : unsigned int      counter

#define N_CLASSES 1000
#define CODE_LEN  64

__global__ void pack_init_kernel(const float* __restrict__ table,
                                 unsigned long long* __restrict__ codes,
                                 unsigned long long* __restrict__ acc,
                                 unsigned int* __restrict__ counter) {
    int gtid = blockIdx.x * blockDim.x + threadIdx.x;
    if (gtid == 0) { *acc = 0ULL; *counter = 0u; }

    int wave = gtid >> 6;          // one 64-lane wave per class
    int lane = threadIdx.x & 63;
    if (wave < N_CLASSES) {
        float v = table[wave * CODE_LEN + lane];          // coalesced 256B/wave
        unsigned long long mask = __ballot(v > 0.5f);     // 64-bit ballot
        if (lane == 0) codes[wave] = mask;
    }
}

__global__ void __launch_bounds__(256)
hamming_finalize_kernel(const int* __restrict__ out_idx,
                        const int* __restrict__ tgt_idx,
                        const unsigned long long* __restrict__ codes,
                        unsigned long long* __restrict__ acc,
                        unsigned int* __restrict__ counter,
                        float* __restrict__ out,
                        int nvec, int n) {
    __shared__ unsigned long long s_codes[N_CLASSES];
    for (int i = threadIdx.x; i < N_CLASSES; i += blockDim.x)
        s_codes[i] = codes[i];
    __syncthreads();

    const int4* o4 = (const int4*)out_idx;
    const int4* t4 = (const int4*)tgt_idx;

    int sum = 0;
    int stride = gridDim.x * blockDim.x;
    for (int i = blockIdx.x * blockDim.x + threadIdx.x; i < nvec; i += stride) {
        int4 o = o4[i];
        int4 t = t4[i];
        sum += __popcll(s_codes[o.x] ^ s_codes[t.x]);
        sum += __popcll(s_codes[o.y] ^ s_codes[t.y]);
        sum += __popcll(s_codes[o.z] ^ s_codes[t.z]);
        sum += __popcll(s_codes[o.w] ^ s_codes[t.w]);
    }
    // scalar tail (n % 4)
    for (int i = nvec * 4 + blockIdx.x * blockDim.x + threadIdx.x; i < n; i += stride) {
        sum += __popcll(s_codes[out_idx[i]] ^ s_codes[tgt_idx[i]]);
    }

    // 64-lane wave reduce
    #pragma unroll
    for (int off = 32; off >= 1; off >>= 1)
        sum += __shfl_down(sum, off);

    __shared__ int s_part[4];      // 256 threads = 4 waves
    int wid  = threadIdx.x >> 6;
    int lane = threadIdx.x & 63;
    if (lane == 0) s_part[wid] = sum;
    __syncthreads();

    if (threadIdx.x == 0) {
        unsigned long long tot =
            (unsigned long long)(s_part[0] + s_part[1] + s_part[2] + s_part[3]);
        atomicAdd(acc, tot);
        __threadfence();                           // release: acc-add before ctr-add
        unsigned int done = atomicAdd(counter, 1u);
        if (done == gridDim.x - 1) {               // last block to finish
            __threadfence();                       // acquire
            unsigned long long total = atomicAdd(acc, 0ULL);  // coherent re-read
            out[0] = (float)((double)total / (double)n);
        }
    }
}

extern "C" void kernel_launch(void* const* d_in, const int* in_sizes, int n_in,
                              void* d_out, int out_size, void* d_ws, size_t ws_size,
                              hipStream_t stream) {
    const int*   out_idx = (const int*)d_in[0];
    const int*   tgt_idx = (const int*)d_in[1];
    const float* table   = (const float*)d_in[2];
    float*       out     = (float*)d_out;

    int n = in_sizes[0];

    unsigned long long* codes   = (unsigned long long*)d_ws;
    unsigned long long* acc     = (unsigned long long*)((char*)d_ws + 8192);
    unsigned int*       counter = (unsigned int*)((char*)d_ws + 8200);

    // 1) pack table -> u64 codes; zero acc/counter
    {
        int threads = 256;                               // 4 waves/block
        int blocks = (N_CLASSES * 64 + threads - 1) / threads;  // 250
        pack_init_kernel<<<blocks, threads, 0, stream>>>(table, codes, acc, counter);
    }

    // 2) main reduce + last-block finalize
    {
        int nvec = n / 4;
        int threads = 256;
        int blocks = 1024;                               // 2 int4 iters/thread at B=2M
        int max_blocks = (nvec + threads - 1) / threads;
        if (blocks > max_blocks) blocks = max_blocks;
        if (blocks < 1) blocks = 1;
        hamming_finalize_kernel<<<blocks, threads, 0, stream>>>(
            out_idx, tgt_idx, codes, acc, counter, out, nvec, n);
    }
}

// Round 3
// 25.424 us; speedup vs baseline: 1.5369x; 1.4926x over previous
//
#include <hip/hip_runtime.h>

// HammingLoss: loss = mean_i popcount(code[output[i]] ^ code[target[i]])
// code[c] = 64-bit packing of coding_table[c, :] (values are exactly 0.0/1.0).
//
// 2 dispatches:
//   1) pack_init: table -> packed u64 codes (one 64-lane wave per class,
//      __ballot); zeroes acc + counter (ws is poisoned 0xAA once and never
//      re-poisoned, so every call must self-init).
//   2) hamming_finalize: LDS-staged popcount reduce + last-block-done finalize
//      (release fence -> counter; last block acquire-fences and atomically
//      re-reads acc -- correct across non-coherent per-XCD L2s).
//
// Device-time budget: hamming reads 16.8 MB of indices -> 2.7 us BW floor.
// Measured window is dominated by per-replay harness overhead (~36 us fixed;
// node removal R1->R2 moved only 1.1 us), so only micro-opts remain:
//   - 512 blocks x 4 int4-iters/thread (was 1024 x 2): better MLP, half the
//     staging traffic + atomics
//   - iter-0 index loads issued BEFORE LDS staging (latency hides under
//     staging + barrier)
//   - 16B vectorized staging of the 8 KB code table
//
// ws layout:
//   [0,    8000) : unsigned long long codes[1000]
//   [8192, 8200) : unsigned long long acc
//   [8200, 8204) : unsigned int      counter

#define N_CLASSES 1000
#define CODE_LEN  64

__global__ void pack_init_kernel(const float* __restrict__ table,
                                 unsigned long long* __restrict__ codes,
                                 unsigned long long* __restrict__ acc,
                                 unsigned int* __restrict__ counter) {
    int gtid = blockIdx.x * blockDim.x + threadIdx.x;
    if (gtid == 0) { *acc = 0ULL; *counter = 0u; }

    int wave = gtid >> 6;          // one 64-lane wave per class
    int lane = threadIdx.x & 63;
    if (wave < N_CLASSES) {
        float v = table[wave * CODE_LEN + lane];          // coalesced 256B/wave
        unsigned long long mask = __ballot(v > 0.5f);     // 64-bit ballot
        if (lane == 0) codes[wave] = mask;
    }
}

__global__ void __launch_bounds__(256)
hamming_finalize_kernel(const int* __restrict__ out_idx,
                        const int* __restrict__ tgt_idx,
                        const unsigned long long* __restrict__ codes,
                        unsigned long long* __restrict__ acc,
                        unsigned int* __restrict__ counter,
                        float* __restrict__ out,
                        int nvec, int n) {
    __shared__ unsigned long long s_codes[N_CLASSES];

    const int4* o4 = (const int4*)out_idx;
    const int4* t4 = (const int4*)tgt_idx;

    int tid0   = blockIdx.x * blockDim.x + threadIdx.x;
    int stride = gridDim.x * blockDim.x;

    // issue iteration-0 global loads early: latency hides under LDS staging
    int4 o0, t0;
    bool have0 = (tid0 < nvec);
    if (have0) { o0 = o4[tid0]; t0 = t4[tid0]; }

    // stage packed table (8 KB) as 16B vectors
    {
        const ulonglong2* src = (const ulonglong2*)codes;
        ulonglong2*       dst = (ulonglong2*)s_codes;
        for (int i = threadIdx.x; i < N_CLASSES / 2; i += blockDim.x)
            dst[i] = src[i];
    }
    __syncthreads();

    int sum = 0;
    if (have0) {
        sum += __popcll(s_codes[o0.x] ^ s_codes[t0.x]);
        sum += __popcll(s_codes[o0.y] ^ s_codes[t0.y]);
        sum += __popcll(s_codes[o0.z] ^ s_codes[t0.z]);
        sum += __popcll(s_codes[o0.w] ^ s_codes[t0.w]);
    }
    for (int i = tid0 + stride; i < nvec; i += stride) {
        int4 o = o4[i];
        int4 t = t4[i];
        sum += __popcll(s_codes[o.x] ^ s_codes[t.x]);
        sum += __popcll(s_codes[o.y] ^ s_codes[t.y]);
        sum += __popcll(s_codes[o.z] ^ s_codes[t.z]);
        sum += __popcll(s_codes[o.w] ^ s_codes[t.w]);
    }
    // scalar tail (n % 4)
    for (int i = nvec * 4 + tid0; i < n; i += stride) {
        sum += __popcll(s_codes[out_idx[i]] ^ s_codes[tgt_idx[i]]);
    }

    // 64-lane wave reduce
    #pragma unroll
    for (int off = 32; off >= 1; off >>= 1)
        sum += __shfl_down(sum, off);

    __shared__ int s_part[4];      // 256 threads = 4 waves
    int wid  = threadIdx.x >> 6;
    int lane = threadIdx.x & 63;
    if (lane == 0) s_part[wid] = sum;
    __syncthreads();

    if (threadIdx.x == 0) {
        unsigned long long tot =
            (unsigned long long)(s_part[0] + s_part[1] + s_part[2] + s_part[3]);
        atomicAdd(acc, tot);
        __threadfence();                           // release: acc-add before ctr-add
        unsigned int done = atomicAdd(counter, 1u);
        if (done == gridDim.x - 1) {               // last block to finish
            __threadfence();                       // acquire
            unsigned long long total = atomicAdd(acc, 0ULL);  // coherent re-read
            out[0] = (float)((double)total / (double)n);
        }
    }
}

extern "C" void kernel_launch(void* const* d_in, const int* in_sizes, int n_in,
                              void* d_out, int out_size, void* d_ws, size_t ws_size,
                              hipStream_t stream) {
    const int*   out_idx = (const int*)d_in[0];
    const int*   tgt_idx = (const int*)d_in[1];
    const float* table   = (const float*)d_in[2];
    float*       out     = (float*)d_out;

    int n = in_sizes[0];

    unsigned long long* codes   = (unsigned long long*)d_ws;
    unsigned long long* acc     = (unsigned long long*)((char*)d_ws + 8192);
    unsigned int*       counter = (unsigned int*)((char*)d_ws + 8200);

    // 1) pack table -> u64 codes; zero acc/counter
    {
        int threads = 256;                               // 4 waves/block
        int blocks = (N_CLASSES * 64 + threads - 1) / threads;  // 250
        pack_init_kernel<<<blocks, threads, 0, stream>>>(table, codes, acc, counter);
    }

    // 2) main reduce + last-block finalize
    {
        int nvec = n / 4;
        int threads = 256;
        int blocks = 512;                                // 4 int4 iters/thread at B=2M
        int max_blocks = (nvec + threads - 1) / threads;
        if (blocks > max_blocks) blocks = max_blocks;
        if (blocks < 1) blocks = 1;
        hamming_finalize_kernel<<<blocks, threads, 0, stream>>>(
            out_idx, tgt_idx, codes, acc, counter, out, nvec, n);
    }
}